// Round 4
// baseline (86.888 us; speedup 1.0000x reference)
//
#include <hip/hip_runtime.h>
#include <cmath>

namespace {
constexpr int B_ = 2, K_ = 4, D_ = 128, L_ = 4096, N_ = 16, R_ = 8, C_ = 40;
constexpr float LOG2E = 1.44269504f;
}

#if __has_builtin(__builtin_amdgcn_exp2f)
#define FEXP2(x) __builtin_amdgcn_exp2f(x)
#else
#define FEXP2(x) exp2f(x)
#endif

// ---------------------------------------------------------------------------
// K1: projections. Grid 256 blocks (b,k,32 l-tiles of 128). Block = 640 thr =
// 10 waves; wave w computes 4 channels: w0-5 kv path (dts 0..7, B 0..15),
// w6-9 q path (C 0..15). Lane = (dg, lq): dg = d-half, lq covers 32 float4
// l-slots. acc[4ch][4l] in regs; halves combined via shfl_xor(32); direct
// coalesced float4 global writes.
// ---------------------------------------------------------------------------
__global__ __launch_bounds__(640, 2) void k1_proj(
    const float* __restrict__ qx, const float* __restrict__ kv,
    const float* __restrict__ xw,   // (K, 40, D)
    float* __restrict__ dtsT,       // (B,K,L,8)
    float* __restrict__ BT,         // (B,K,L,16)
    float* __restrict__ CT)         // (B,K,L,16)
{
    __shared__ float Wt[D_ * C_];   // [d][c]

    const int tid = threadIdx.x;
    const int w = tid >> 6, lane = tid & 63;
    const int dg = lane >> 5, lq = lane & 31;
    int blk = blockIdx.x;
    const int lt = blk & 31; blk >>= 5;
    const int k = blk & 3; const int b = blk >> 2;
    const int bk = b * K_ + k;

    for (int i = tid; i < C_ * D_; i += 640) {
        const int c = i >> 7, d = i & 127;
        Wt[d * C_ + c] = xw[(k * C_ + c) * D_ + d];
    }
    __syncthreads();

    const float* xsrc = (w >= 6) ? qx : kv;
    const int c0 = w * 4;
    float acc[4][4];
    #pragma unroll
    for (int c = 0; c < 4; ++c)
        #pragma unroll
        for (int j = 0; j < 4; ++j) acc[c][j] = 0.f;

    const float* src = xsrc + ((size_t)bk * D_ + dg * 64) * L_ + lt * 128 + 4 * lq;
    #pragma unroll 8
    for (int dd = 0; dd < 64; ++dd) {
        const float4 x = *(const float4*)(src + (size_t)dd * L_);
        const float4 wv = *(const float4*)&Wt[(dg * 64 + dd) * C_ + c0];
        const float* wp = (const float*)&wv;
        #pragma unroll
        for (int c = 0; c < 4; ++c) {
            acc[c][0] = fmaf(x.x, wp[c], acc[c][0]);
            acc[c][1] = fmaf(x.y, wp[c], acc[c][1]);
            acc[c][2] = fmaf(x.z, wp[c], acc[c][2]);
            acc[c][3] = fmaf(x.w, wp[c], acc[c][3]);
        }
    }

    #pragma unroll
    for (int c = 0; c < 4; ++c)
        #pragma unroll
        for (int j = 0; j < 4; ++j)
            acc[c][j] += __shfl_xor(acc[c][j], 32, 64);

    if (dg == 0) {
        #pragma unroll
        for (int j = 0; j < 4; ++j) {
            const int l = lt * 128 + 4 * lq + j;
            float4 o; o.x = acc[0][j]; o.y = acc[1][j]; o.z = acc[2][j]; o.w = acc[3][j];
            if (w < 2)
                *(float4*)(dtsT + ((size_t)bk * L_ + l) * R_ + w * 4) = o;
            else if (w < 6)
                *(float4*)(BT + ((size_t)bk * L_ + l) * N_ + (w - 2) * 4) = o;
            else
                *(float4*)(CT + ((size_t)bk * L_ + l) * N_ + (w - 6) * 4) = o;
        }
    }
}

// ---------------------------------------------------------------------------
// K2: chunk pass 1. Thread = d (128/block = 2 waves), per (b,k,chunk).
// Delta from rank-8 dts in-register; 16 n-states in registers.
// ---------------------------------------------------------------------------
template<int CHUNK>
__global__ __launch_bounds__(128, 2) void k2_pass1(
    const float* __restrict__ kv, const float* __restrict__ dtsT,
    const float* __restrict__ BT, const float* __restrict__ alg,
    const float* __restrict__ dtw, const float* __restrict__ dtb,
    float* __restrict__ hend, float* __restrict__ Ssum)
{
    constexpr int NCH = L_ / CHUNK;
    constexpr int S = CHUNK + 1;
    constexpr int J = CHUNK / 4;
    __shared__ float u_s[D_ * S];
    __shared__ float dts_s[CHUNK * R_];
    __shared__ float B_s[CHUNK * N_];

    const int tid = threadIdx.x;
    const int d = tid;
    int blk = blockIdx.x;
    const int ch = blk % NCH; blk /= NCH;
    const int k = blk % K_; const int b = blk / K_;
    const int bk = b * K_ + k;

    for (int f = tid; f < D_ * J; f += 128) {
        const int d0 = f / J, j4 = (f % J) * 4;
        float4 v = *(const float4*)(kv + ((size_t)bk * D_ + d0) * L_ + ch * CHUNK + j4);
        float* p = &u_s[d0 * S + j4];
        p[0] = v.x; p[1] = v.y; p[2] = v.z; p[3] = v.w;
    }
    {
        const float* src = dtsT + ((size_t)bk * L_ + ch * CHUNK) * R_;
        for (int f = tid; f < CHUNK * 2; f += 128)
            *(float4*)&dts_s[4 * f] = *(const float4*)(src + 4 * f);
        const float* bsrc = BT + ((size_t)bk * L_ + ch * CHUNK) * N_;
        for (int f = tid; f < CHUNK * 4; f += 128)
            *(float4*)&B_s[4 * f] = *(const float4*)(bsrc + 4 * f);
    }
    __syncthreads();

    float dtwr[R_];
    {
        const float* p = dtw + ((size_t)k * D_ + d) * R_;
        *(float4*)&dtwr[0] = *(const float4*)p;
        *(float4*)&dtwr[4] = *(const float4*)(p + 4);
    }
    const float bias = dtb[k * D_ + d];
    float A2[N_];
    {
        const float* ap = alg + ((size_t)k * D_ + d) * N_;
        #pragma unroll
        for (int j = 0; j < 4; ++j) {
            float4 a = *(const float4*)(ap + 4 * j);
            A2[4*j]   = -__expf(a.x) * LOG2E; A2[4*j+1] = -__expf(a.y) * LOG2E;
            A2[4*j+2] = -__expf(a.z) * LOG2E; A2[4*j+3] = -__expf(a.w) * LOG2E;
        }
    }

    float h[N_];
    #pragma unroll
    for (int n = 0; n < N_; ++n) h[n] = 0.f;
    float sd = 0.f;

    #pragma unroll 4
    for (int l = 0; l < CHUNK; ++l) {
        float dv[R_];
        *(float4*)&dv[0] = *(const float4*)&dts_s[l * R_];
        *(float4*)&dv[4] = *(const float4*)&dts_s[l * R_ + 4];
        float s = bias;
        #pragma unroll
        for (int r = 0; r < R_; ++r) s = fmaf(dv[r], dtwr[r], s);
        const float e = FEXP2(s * LOG2E);
        const float dlt = (s > 15.f) ? s : __logf(1.f + e);
        sd += dlt;
        const float xb = dlt * u_s[d * S + l];
        float bv[N_];
        *(float4*)&bv[0]  = *(const float4*)&B_s[l * N_ + 0];
        *(float4*)&bv[4]  = *(const float4*)&B_s[l * N_ + 4];
        *(float4*)&bv[8]  = *(const float4*)&B_s[l * N_ + 8];
        *(float4*)&bv[12] = *(const float4*)&B_s[l * N_ + 12];
        #pragma unroll
        for (int n = 0; n < N_; ++n)
            h[n] = fmaf(FEXP2(dlt * A2[n]), h[n], xb * bv[n]);
    }

    float* hp = hend + (((size_t)bk * NCH + ch) * D_ + d) * N_;
    #pragma unroll
    for (int j = 0; j < 4; ++j) {
        float4 o; o.x = h[4*j]; o.y = h[4*j+1]; o.z = h[4*j+2]; o.w = h[4*j+3];
        *(float4*)(hp + 4 * j) = o;
    }
    Ssum[((size_t)bk * NCH + ch) * D_ + d] = sd;
}

// ---------------------------------------------------------------------------
// K2.5: serial chunk chain, hend -> hinit (exclusive prefix). 256 blocks x
// 1 wave (thread = (bk,d,n)); 32-deep batched coalesced loads for latency.
// ---------------------------------------------------------------------------
template<int NCH>
__global__ __launch_bounds__(64, 2) void k25_chain(
    const float* __restrict__ alg, const float* __restrict__ Ssum,
    const float* __restrict__ hend, float* __restrict__ hinit)
{
    const int tg = blockIdx.x * 64 + threadIdx.x;   // 16384 threads
    const int n = tg & 15;
    const int d = (tg >> 4) & 127;
    const int bk = tg >> 11;
    const int k = bk & 3;

    const float A2 = -__expf(alg[((size_t)k * D_ + d) * N_ + n]) * LOG2E;
    float h = 0.f;
    for (int c0 = 0; c0 < NCH; c0 += 32) {
        float he[32], ss[32];
        #pragma unroll
        for (int j = 0; j < 32; ++j) {
            const size_t si = ((size_t)bk * NCH + c0 + j) * D_ + d;
            he[j] = hend[si * N_ + n];
            ss[j] = Ssum[si];
        }
        #pragma unroll
        for (int j = 0; j < 32; ++j) {
            const size_t si = ((size_t)bk * NCH + c0 + j) * D_ + d;
            hinit[si * N_ + n] = h;
            h = fmaf(FEXP2(ss[j] * A2), h, he[j]);
        }
    }
}

// ---------------------------------------------------------------------------
// K3: chunk pass 2. Like K2 + C; y = sum_n h*C in registers, staged through
// LDS (scalar, odd stride), flushed with +u*Ds coalesced.
// ---------------------------------------------------------------------------
template<int CHUNK>
__global__ __launch_bounds__(128, 2) void k3_pass2(
    const float* __restrict__ kv, const float* __restrict__ dtsT,
    const float* __restrict__ BT, const float* __restrict__ CT,
    const float* __restrict__ alg, const float* __restrict__ dtw,
    const float* __restrict__ dtb, const float* __restrict__ DsG,
    const float* __restrict__ hinit, float* __restrict__ out)
{
    constexpr int NCH = L_ / CHUNK;
    constexpr int S = CHUNK + 1;
    constexpr int J = CHUNK / 4;
    __shared__ float u_s[D_ * S];
    __shared__ float y_s[D_ * S];
    __shared__ float dts_s[CHUNK * R_];
    __shared__ float B_s[CHUNK * N_];
    __shared__ float C_s[CHUNK * N_];

    const int tid = threadIdx.x;
    const int d = tid;
    int blk = blockIdx.x;
    const int ch = blk % NCH; blk /= NCH;
    const int k = blk % K_; const int b = blk / K_;
    const int bk = b * K_ + k;

    for (int f = tid; f < D_ * J; f += 128) {
        const int d0 = f / J, j4 = (f % J) * 4;
        float4 v = *(const float4*)(kv + ((size_t)bk * D_ + d0) * L_ + ch * CHUNK + j4);
        float* p = &u_s[d0 * S + j4];
        p[0] = v.x; p[1] = v.y; p[2] = v.z; p[3] = v.w;
    }
    {
        const float* src = dtsT + ((size_t)bk * L_ + ch * CHUNK) * R_;
        for (int f = tid; f < CHUNK * 2; f += 128)
            *(float4*)&dts_s[4 * f] = *(const float4*)(src + 4 * f);
        const float* bsrc = BT + ((size_t)bk * L_ + ch * CHUNK) * N_;
        const float* csrc = CT + ((size_t)bk * L_ + ch * CHUNK) * N_;
        for (int f = tid; f < CHUNK * 4; f += 128) {
            *(float4*)&B_s[4 * f] = *(const float4*)(bsrc + 4 * f);
            *(float4*)&C_s[4 * f] = *(const float4*)(csrc + 4 * f);
        }
    }
    __syncthreads();

    float dtwr[R_];
    {
        const float* p = dtw + ((size_t)k * D_ + d) * R_;
        *(float4*)&dtwr[0] = *(const float4*)p;
        *(float4*)&dtwr[4] = *(const float4*)(p + 4);
    }
    const float bias = dtb[k * D_ + d];
    float A2[N_];
    {
        const float* ap = alg + ((size_t)k * D_ + d) * N_;
        #pragma unroll
        for (int j = 0; j < 4; ++j) {
            float4 a = *(const float4*)(ap + 4 * j);
            A2[4*j]   = -__expf(a.x) * LOG2E; A2[4*j+1] = -__expf(a.y) * LOG2E;
            A2[4*j+2] = -__expf(a.z) * LOG2E; A2[4*j+3] = -__expf(a.w) * LOG2E;
        }
    }

    float h[N_];
    {
        const float* hp = hinit + (((size_t)bk * NCH + ch) * D_ + d) * N_;
        #pragma unroll
        for (int j = 0; j < 4; ++j) {
            float4 v = *(const float4*)(hp + 4 * j);
            h[4*j] = v.x; h[4*j+1] = v.y; h[4*j+2] = v.z; h[4*j+3] = v.w;
        }
    }

    #pragma unroll 4
    for (int l = 0; l < CHUNK; ++l) {
        float dv[R_];
        *(float4*)&dv[0] = *(const float4*)&dts_s[l * R_];
        *(float4*)&dv[4] = *(const float4*)&dts_s[l * R_ + 4];
        float s = bias;
        #pragma unroll
        for (int r = 0; r < R_; ++r) s = fmaf(dv[r], dtwr[r], s);
        const float e = FEXP2(s * LOG2E);
        const float dlt = (s > 15.f) ? s : __logf(1.f + e);
        const float xb = dlt * u_s[d * S + l];
        float bv[N_], cv[N_];
        *(float4*)&bv[0]  = *(const float4*)&B_s[l * N_ + 0];
        *(float4*)&bv[4]  = *(const float4*)&B_s[l * N_ + 4];
        *(float4*)&bv[8]  = *(const float4*)&B_s[l * N_ + 8];
        *(float4*)&bv[12] = *(const float4*)&B_s[l * N_ + 12];
        *(float4*)&cv[0]  = *(const float4*)&C_s[l * N_ + 0];
        *(float4*)&cv[4]  = *(const float4*)&C_s[l * N_ + 4];
        *(float4*)&cv[8]  = *(const float4*)&C_s[l * N_ + 8];
        *(float4*)&cv[12] = *(const float4*)&C_s[l * N_ + 12];
        float p0 = 0.f, p1 = 0.f, p2 = 0.f, p3 = 0.f;
        #pragma unroll
        for (int n = 0; n < N_; ++n) {
            h[n] = fmaf(FEXP2(dlt * A2[n]), h[n], xb * bv[n]);
            if ((n & 3) == 0)      p0 = fmaf(h[n], cv[n], p0);
            else if ((n & 3) == 1) p1 = fmaf(h[n], cv[n], p1);
            else if ((n & 3) == 2) p2 = fmaf(h[n], cv[n], p2);
            else                   p3 = fmaf(h[n], cv[n], p3);
        }
        y_s[d * S + l] = (p0 + p1) + (p2 + p3);
    }
    __syncthreads();

    for (int f = tid; f < D_ * J; f += 128) {
        const int d0 = f / J, j4 = (f % J) * 4;
        const float Dv = DsG[k * D_ + d0];
        const float* yp = &y_s[d0 * S + j4];
        const float* up = &u_s[d0 * S + j4];
        float4 o;
        o.x = fmaf(up[0], Dv, yp[0]); o.y = fmaf(up[1], Dv, yp[1]);
        o.z = fmaf(up[2], Dv, yp[2]); o.w = fmaf(up[3], Dv, yp[3]);
        *(float4*)(out + ((size_t)bk * D_ + d0) * L_ + ch * CHUNK + j4) = o;
    }
}

extern "C" void kernel_launch(void* const* d_in, const int* in_sizes, int n_in,
                              void* d_out, int out_size, void* d_ws, size_t ws_size,
                              hipStream_t stream)
{
    const float* qx  = (const float*)d_in[0];
    const float* kv  = (const float*)d_in[1];
    const float* xw  = (const float*)d_in[2];
    const float* dtw = (const float*)d_in[3];
    const float* dtb = (const float*)d_in[4];
    const float* alg = (const float*)d_in[5];
    const float* Ds  = (const float*)d_in[6];
    float* out = (float*)d_out;

    const size_t sz_dts = (size_t)B_ * K_ * L_ * R_;   // 262,144
    const size_t sz_bc  = (size_t)B_ * K_ * L_ * N_;   // 524,288

    auto need = [&](int NCH) {
        return (sz_dts + 2 * sz_bc
                + 2 * (size_t)B_ * K_ * NCH * D_ * N_
                + (size_t)B_ * K_ * NCH * D_) * sizeof(float);
    };

    float* dts = (float*)d_ws;
    float* BTp = dts + sz_dts;
    float* CTp = BTp + sz_bc;
    float* hend = CTp + sz_bc;

    k1_proj<<<B_ * K_ * 32, 640, 0, stream>>>(qx, kv, xw, dts, BTp, CTp);

    if (ws_size >= need(64)) {
        constexpr int CHUNK = 64, NCH = 64;
        const size_t sz_h = (size_t)B_ * K_ * NCH * D_ * N_;
        float* hinit = hend + sz_h;
        float* Ssm = hinit + sz_h;
        k2_pass1<CHUNK><<<B_ * K_ * NCH, 128, 0, stream>>>(kv, dts, BTp, alg, dtw, dtb, hend, Ssm);
        k25_chain<NCH><<<256, 64, 0, stream>>>(alg, Ssm, hend, hinit);
        k3_pass2<CHUNK><<<B_ * K_ * NCH, 128, 0, stream>>>(kv, dts, BTp, CTp, alg, dtw, dtb, Ds, hinit, out);
    } else if (ws_size >= need(32)) {
        constexpr int CHUNK = 128, NCH = 32;
        const size_t sz_h = (size_t)B_ * K_ * NCH * D_ * N_;
        float* hinit = hend + sz_h;
        float* Ssm = hinit + sz_h;
        k2_pass1<CHUNK><<<B_ * K_ * NCH, 128, 0, stream>>>(kv, dts, BTp, alg, dtw, dtb, hend, Ssm);
        k25_chain<NCH><<<256, 64, 0, stream>>>(alg, Ssm, hend, hinit);
        k3_pass2<CHUNK><<<B_ * K_ * NCH, 128, 0, stream>>>(kv, dts, BTp, CTp, alg, dtw, dtb, Ds, hinit, out);
    }
}